// Round 5
// baseline (2092.320 us; speedup 1.0000x reference)
//
#include <hip/hip_runtime.h>
#include <hip/hip_bf16.h>

// DeepLSTM on MI355X — v5: x-half precompute + 1-barrier steps + no global ops
// in the recurrent loop.
//
// v4 post-mortem: steady state ~5700 cyc/step vs 1240 cyc MFMA floor; inner
// loop (2 barriers + global-store drains + thin ILP) dominated, not sync.
// v5: per chunk (CT=4): phase1 computes gx[tl] = x_tl @ W_ih densely into
// 64 VGPRs (no barriers); phase2 per-step = 16 MFMAs (h @ W_hh) + activation
// + LDS h double-buffer + ONE barrier; phase3 bulk ring store from hhist +
// per-chunk flag publish (l<7) or batched out-projection (l=7).
//
// Grid: 32 blocks x 512 threads; block (l,g) = layer l, batch group g (16 rows).
// ws: [0,8KB) flags (prod@0, cons@4KB, 128B stride); [8KB,...) ring
//     [pair][RING_T][16][128] bf16.

#define T_ 512
#define L_ 8
#define H_ 128
#define G4_ 512
#define OUT_ 65
#define B_ 64
#define NG_ 4
#define BG_ 16
#define LDSW_ 136                          // padded LDS row stride (bf16)
#define HT_OFF_ (B_ * T_ * OUT_)           // 2129920
#define CT_OFF_ (HT_OFF_ + L_ * B_ * H_)   // 2195456
#define STEP_U64_ 512                      // one step's h-tile: 16x128 bf16 = 4KB

typedef __bf16 bf16_t;
typedef bf16_t bf16x8 __attribute__((ext_vector_type(8)));
typedef bf16_t bf16x4 __attribute__((ext_vector_type(4)));
typedef float f32x4 __attribute__((ext_vector_type(4)));
typedef unsigned long long u64;

__device__ __forceinline__ float sigm(float x) { return 1.f / (1.f + __expf(-x)); }
__device__ __forceinline__ float tanh_fast(float x) {
  float e = __expf(-2.f * fabsf(x));
  float r = (1.f - e) / (1.f + e);
  return copysignf(r, x);
}
__device__ __forceinline__ int flag_ld(int* p) {
  return __hip_atomic_load(p, __ATOMIC_RELAXED, __HIP_MEMORY_SCOPE_AGENT);
}
__device__ __forceinline__ void flag_st(int* p, int v) {
  __hip_atomic_store(p, v, __ATOMIC_RELAXED, __HIP_MEMORY_SCOPE_AGENT);
}

__global__ void zero_flags(int* flags) { flags[blockIdx.x * 1024 + threadIdx.x] = 0; }

template <int CT, int RING_T>
__global__ __launch_bounds__(512, 2)
void lstm_pipe(const int* __restrict__ xids, const float* __restrict__ embed,
               const float* __restrict__ wih_g, const float* __restrict__ bih_g,
               const float* __restrict__ whh_g, const float* __restrict__ bhh_g,
               const float* __restrict__ wout_g, const float* __restrict__ bout_g,
               float* __restrict__ out, int* __restrict__ flags,
               u64* __restrict__ ring) {
  const int l    = blockIdx.x >> 2;
  const int g    = blockIdx.x & 3;
  const int tid  = threadIdx.x;
  const int wv   = tid >> 6;      // wave 0..7: gate col-tiles {wv, wv+8, wv+16, wv+24}
  const int lane = tid & 63;
  const int q    = lane >> 4;     // quad 0..3
  const int col  = lane & 15;

  __shared__ __align__(16) bf16_t xchunk[CT * 16 * LDSW_];  // chunk input, A-layout
  __shared__ __align__(16) bf16_t hbuf[2][16 * LDSW_];      // h state, double-buffered
  __shared__ __align__(16) bf16_t hhist[CT * 16 * LDSW_];   // chunk h history

  // ---- resident weight fragments (bf16, B-layout: lane holds B[k][n], n=col) ----
  bf16x8 wih[4][4], whh[4][4];  // [gate-class c][k-tile kt]
#pragma unroll
  for (int c = 0; c < 4; ++c) {
    const int n = wv * 16 + c * 128 + col;
#pragma unroll
    for (int kt = 0; kt < 4; ++kt) {
      bf16x8 a, b;
#pragma unroll
      for (int jj = 0; jj < 8; ++jj) {
        const int k = kt * 32 + q * 8 + jj;
        a[jj] = (bf16_t)wih_g[(l * H_ + k) * G4_ + n];
        b[jj] = (bf16_t)whh_g[(l * H_ + k) * G4_ + n];
      }
      wih[c][kt] = a;
      whh[c][kt] = b;
    }
  }
  float bias[4];
#pragma unroll
  for (int c = 0; c < 4; ++c) {
    const int n = wv * 16 + c * 128 + col;
    bias[c] = bih_g[l * G4_ + n] + bhh_g[l * G4_ + n];
  }
  bf16x8 wout[4];
  float bo = 0.f;
  const bool has_out = (l == L_ - 1) && (wv < 5);
  if (has_out) {
    const int n = wv * 16 + col;
#pragma unroll
    for (int kt = 0; kt < 4; ++kt) {
      bf16x8 a;
#pragma unroll
      for (int jj = 0; jj < 8; ++jj) {
        const int k = kt * 32 + q * 8 + jj;
        a[jj] = (n < OUT_) ? (bf16_t)wout_g[k * OUT_ + n] : (bf16_t)(0.f);
      }
      wout[kt] = a;
    }
    if (n < OUT_) bo = bout_g[n];
  }

  for (int i = tid; i < 16 * LDSW_; i += 512) hbuf[0][i] = (bf16_t)(0.f);
  float cst[4] = {0.f, 0.f, 0.f, 0.f};  // c-state: rows m=q*4+r, col j=16*wv+col
  int pr = 0;                            // current h_{t-1} buffer index
  __syncthreads();

  int* myprod   = flags + ((l * NG_ + g) << 5);
  int* prevprod = (l > 0) ? flags + (((l - 1) * NG_ + g) << 5) : flags;
  int* mycons   = flags + 1024 + ((l * NG_ + g) << 5);
  int* nextcons = (l < L_ - 1) ? flags + 1024 + (((l + 1) * NG_ + g) << 5) : flags;
  u64* myring  = (l < L_ - 1) ? ring + (size_t)(l * NG_ + g) * RING_T * STEP_U64_ : ring;
  const u64* srcring = (l > 0) ? ring + (size_t)((l - 1) * NG_ + g) * RING_T * STEP_U64_ : ring;

  const int aoff = col * LDSW_ + q * 8;  // A-fragment: m=lane&15, k=q*8+j
  int seen_prod = 0, seen_cons = 0;      // tid0-cached monotonic flags

#pragma unroll 1
  for (int ch = 0; ch < T_ / CT; ++ch) {
    const int t0 = ch * CT;

    // ================= chunk input acquire =================
    if (l == 0) {
      const int m  = tid >> 5;
      const int c4 = (tid & 31) << 2;
#pragma unroll
      for (int tl = 0; tl < CT; ++tl) {
        const int token = xids[(g * BG_ + m) * T_ + t0 + tl];
        const float4 e = *(const float4*)(embed + token * H_ + c4);
        bf16x4 v;
        v[0] = (bf16_t)e.x; v[1] = (bf16_t)e.y; v[2] = (bf16_t)e.z; v[3] = (bf16_t)e.w;
        *(bf16x4*)(&xchunk[(tl * 16 + m) * LDSW_ + c4]) = v;
      }
      __syncthreads();  // xchunk ready (also gates prior phase-3 hhist readers)
    } else {
      if (tid == 0) {
        const int target = t0 + CT;
        if (seen_prod < target) {
          int v;
          do { v = flag_ld(prevprod); } while (v < target);
          seen_prod = v;
        }
      }
      __syncthreads();  // gate all waves on poll; also ends prior phase-3 reads
      __builtin_amdgcn_fence(__ATOMIC_ACQUIRE, "agent");
      const int idx = tid >> 2;  // row id
      if (idx < CT * 16) {
        const int tl = idx >> 4, m = idx & 15, seg = tid & 3;
        const u64* src = srcring + (size_t)((t0 + tl) & (RING_T - 1)) * STEP_U64_ + m * 32 + seg * 8;
        bf16_t* dst = &xchunk[(tl * 16 + m) * LDSW_ + seg * 32];
#pragma unroll
        for (int j = 0; j < 4; ++j) *(uint4*)(dst + j * 8) = *(const uint4*)(src + j * 2);
      }
      __syncthreads();  // xchunk ready
      if (RING_T < T_ && tid == 0) flag_st(mycons, t0 + CT);
    }

    // slot-reuse back-pressure (only when ring smaller than history)
    if (RING_T < T_ && l < L_ - 1 && t0 + CT > RING_T) {
      if (tid == 0) {
        const int need = t0 + CT - RING_T;
        if (seen_cons < need) {
          int v;
          do { v = flag_ld(nextcons); } while (v < need);
          seen_cons = v;
        }
      }
      __syncthreads();
    }

    // ================= phase 1: dense x-half, gx[tl] = x_tl @ W_ih =================
    f32x4 gx[CT][4];
#pragma unroll
    for (int tl = 0; tl < CT; ++tl) {
#pragma unroll
      for (int c = 0; c < 4; ++c) gx[tl][c] = (f32x4){0.f, 0.f, 0.f, 0.f};
      bf16x8 xa[4];
      const int xoff = (tl * 16 + col) * LDSW_ + q * 8;
#pragma unroll
      for (int kt = 0; kt < 4; ++kt) xa[kt] = *(const bf16x8*)(&xchunk[xoff + kt * 32]);
#pragma unroll
      for (int c = 0; c < 4; ++c)
#pragma unroll
        for (int kt = 0; kt < 4; ++kt)
          gx[tl][c] = __builtin_amdgcn_mfma_f32_16x16x32_bf16(xa[kt], wih[c][kt], gx[tl][c], 0, 0, 0);
    }

    // ================= phase 2: CT recurrent steps (LDS-only, 1 barrier each) ======
#pragma unroll 1
    for (int tl = 0; tl < CT; ++tl) {
      const int t = t0 + tl;
      bf16x8 ha[4];
#pragma unroll
      for (int kt = 0; kt < 4; ++kt)
        ha[kt] = *(const bf16x8*)(&hbuf[pr][aoff + kt * 32]);
      f32x4 acc[4];
#pragma unroll
      for (int c = 0; c < 4; ++c) acc[c] = gx[tl][c];
#pragma unroll
      for (int c = 0; c < 4; ++c)
#pragma unroll
        for (int kt = 0; kt < 4; ++kt)
          acc[c] = __builtin_amdgcn_mfma_f32_16x16x32_bf16(ha[kt], whh[c][kt], acc[c], 0, 0, 0);

      float hv[4];
      bf16_t hb[4];
#pragma unroll
      for (int r = 0; r < 4; ++r) {
        const float iv = sigm(acc[0][r] + bias[0]);
        const float fv = sigm(acc[1][r] + bias[1]);
        const float gv = tanh_fast(acc[2][r] + bias[2]);
        const float ov = sigm(acc[3][r] + bias[3]);
        const float cv = fv * cst[r] + iv * gv;
        cst[r] = cv;
        const float h = ov * tanh_fast(cv);
        hv[r] = h;
        hb[r] = (bf16_t)h;
      }

      {
        const int jc = wv * 16 + col;
#pragma unroll
        for (int r = 0; r < 4; ++r) {
          hbuf[pr ^ 1][(q * 4 + r) * LDSW_ + jc] = hb[r];
          hhist[(tl * 16 + q * 4 + r) * LDSW_ + jc] = hb[r];
        }
      }
      if (t == T_ - 1) {  // final hT / cT (once)
        const int jc = wv * 16 + col;
#pragma unroll
        for (int r = 0; r < 4; ++r) {
          const int b = g * BG_ + q * 4 + r;
          out[HT_OFF_ + (l * B_ + b) * H_ + jc] = hv[r];
          out[CT_OFF_ + (l * B_ + b) * H_ + jc] = cst[r];
        }
      }
      __syncthreads();  // h_t published; hhist[tl] ready
      pr ^= 1;
    }

    // ================= phase 3: bulk handoff / batched out-projection =============
    if (l < L_ - 1) {
      const int idx = tid >> 2;
      if (idx < CT * 16) {
        const int tl = idx >> 4, m = idx & 15, seg = tid & 3;
        const bf16_t* src = &hhist[(tl * 16 + m) * LDSW_ + seg * 32];
        u64* dst = myring + (size_t)((t0 + tl) & (RING_T - 1)) * STEP_U64_ + m * 32 + seg * 8;
#pragma unroll
        for (int j = 0; j < 4; ++j) *(uint4*)(dst + j * 2) = *(const uint4*)(src + j * 8);
      }
      __syncthreads();  // per-wave vmcnt(0) drain => all ring stores complete
      if (tid == 0) {
        __builtin_amdgcn_fence(__ATOMIC_RELEASE, "agent");
        flag_st(myprod, t0 + CT);
      }
    } else if (has_out) {
      const int n = wv * 16 + col;
#pragma unroll
      for (int tl = 0; tl < CT; ++tl) {
        f32x4 oacc = (f32x4){0.f, 0.f, 0.f, 0.f};
#pragma unroll
        for (int kt = 0; kt < 4; ++kt) {
          const bf16x8 a = *(const bf16x8*)(&hhist[(tl * 16 + col) * LDSW_ + kt * 32 + q * 8]);
          oacc = __builtin_amdgcn_mfma_f32_16x16x32_bf16(a, wout[kt], oacc, 0, 0, 0);
        }
        if (n < OUT_) {
#pragma unroll
          for (int r = 0; r < 4; ++r) {
            const int b = g * BG_ + q * 4 + r;
            out[(b * T_ + (t0 + tl)) * OUT_ + n] = oacc[r] + bo;
          }
        }
      }
    }
  }
}

extern "C" void kernel_launch(void* const* d_in, const int* in_sizes, int n_in,
                              void* d_out, int out_size, void* d_ws, size_t ws_size,
                              hipStream_t stream) {
  (void)in_sizes; (void)n_in; (void)out_size;
  const int*   x     = (const int*)d_in[0];
  const float* embed = (const float*)d_in[1];
  const float* w_ih  = (const float*)d_in[2];
  const float* b_ih  = (const float*)d_in[3];
  const float* w_hh  = (const float*)d_in[4];
  const float* b_hh  = (const float*)d_in[5];
  const float* w_out = (const float*)d_in[6];
  const float* b_out = (const float*)d_in[7];
  float* out = (float*)d_out;

  int* flags = (int*)d_ws;                     // 8 KB: prod@0, cons@4KB
  u64* ring  = (u64*)((char*)d_ws + 8192);

  hipLaunchKernelGGL(zero_flags, dim3(2), dim3(1024), 0, stream, flags);

  auto need = [&](int ring_t) { return (size_t)8192 + (size_t)28 * ring_t * 4096; };

  if (ws_size >= need(512)) {        // 57 MB: full history, no back-pressure
    hipLaunchKernelGGL((lstm_pipe<4, 512>), dim3(L_ * NG_), dim3(512), 0, stream,
                       x, embed, w_ih, b_ih, w_hh, b_hh, w_out, b_out, out, flags, ring);
  } else if (ws_size >= need(16)) {  // 1.8 MB
    hipLaunchKernelGGL((lstm_pipe<4, 16>), dim3(L_ * NG_), dim3(512), 0, stream,
                       x, embed, w_ih, b_ih, w_hh, b_hh, w_out, b_out, out, flags, ring);
  } else if (ws_size >= need(8)) {   // 0.92 MB
    hipLaunchKernelGGL((lstm_pipe<4, 8>), dim3(L_ * NG_), dim3(512), 0, stream,
                       x, embed, w_ih, b_ih, w_hh, b_hh, w_out, b_out, out, flags, ring);
  } else {                           // 0.47 MB worst case
    hipLaunchKernelGGL((lstm_pipe<4, 4>), dim3(L_ * NG_), dim3(512), 0, stream,
                       x, embed, w_ih, b_ih, w_hh, b_hh, w_out, b_out, out, flags, ring);
  }
}

// Round 6
// 1455.745 us; speedup vs baseline: 1.4373x; 1.4373x over previous
//
#include <hip/hip_runtime.h>
#include <hip/hip_bf16.h>

// DeepLSTM on MI355X — v6: v5 structure with the scratch-spill fixed.
//
// v5 post-mortem: gx[CT][4] was indexed by the induction var of a
// '#pragma unroll 1' loop -> dynamic register-array indexing -> compiler
// placed all of gx in SCRATCH. WRITE_SIZE 596 MB (= 512thr x 256B x 32blk
// x 128 chunks = 537 MB round-trip), 2092 us. v6: phase 2 fully unrolled
// (CT=4) so gx indexing is static; h double-buffer parity is compile-time
// (rb = tl&1; CT even => every chunk starts at buffer 0); phase-2 MFMAs
// accumulate IN PLACE into gx[tl] (no separate acc[], -16 VGPRs).
//
// Structure recap: per chunk (CT=4): acquire (l0: embed gather; else poll +
// bulk ring->LDS copy) -> phase1 dense x-half gx[tl] = x_tl @ W_ih (64 MFMA,
// no barriers) -> phase2 per-step h @ W_hh + activation + LDS h flip, ONE
// barrier/step -> phase3 bulk ring store + flag publish (l<7) or batched
// out-projection (l=7). No global ops inside the recurrent step loop.
//
// Grid: 32 blocks x 512 threads; block (l,g) = layer l, batch group g (16 rows).
// ws: [0,8KB) flags (prod@0, cons@4KB, 128B stride); [8KB,...) ring
//     [pair][RING_T][16][128] bf16.

#define T_ 512
#define L_ 8
#define H_ 128
#define G4_ 512
#define OUT_ 65
#define B_ 64
#define NG_ 4
#define BG_ 16
#define LDSW_ 136                          // padded LDS row stride (bf16)
#define HT_OFF_ (B_ * T_ * OUT_)           // 2129920
#define CT_OFF_ (HT_OFF_ + L_ * B_ * H_)   // 2195456
#define STEP_U64_ 512                      // one step's h-tile: 16x128 bf16 = 4KB

typedef __bf16 bf16_t;
typedef bf16_t bf16x8 __attribute__((ext_vector_type(8)));
typedef bf16_t bf16x4 __attribute__((ext_vector_type(4)));
typedef float f32x4 __attribute__((ext_vector_type(4)));
typedef unsigned long long u64;

__device__ __forceinline__ float sigm(float x) { return 1.f / (1.f + __expf(-x)); }
__device__ __forceinline__ float tanh_fast(float x) {
  float e = __expf(-2.f * fabsf(x));
  float r = (1.f - e) / (1.f + e);
  return copysignf(r, x);
}
__device__ __forceinline__ int flag_ld(int* p) {
  return __hip_atomic_load(p, __ATOMIC_RELAXED, __HIP_MEMORY_SCOPE_AGENT);
}
__device__ __forceinline__ void flag_st(int* p, int v) {
  __hip_atomic_store(p, v, __ATOMIC_RELAXED, __HIP_MEMORY_SCOPE_AGENT);
}

__global__ void zero_flags(int* flags) { flags[blockIdx.x * 1024 + threadIdx.x] = 0; }

template <int CT, int RING_T>
__global__ __launch_bounds__(512, 2)
void lstm_pipe(const int* __restrict__ xids, const float* __restrict__ embed,
               const float* __restrict__ wih_g, const float* __restrict__ bih_g,
               const float* __restrict__ whh_g, const float* __restrict__ bhh_g,
               const float* __restrict__ wout_g, const float* __restrict__ bout_g,
               float* __restrict__ out, int* __restrict__ flags,
               u64* __restrict__ ring) {
  static_assert((CT & 1) == 0, "CT must be even (h buffer parity)");
  const int l    = blockIdx.x >> 2;
  const int g    = blockIdx.x & 3;
  const int tid  = threadIdx.x;
  const int wv   = tid >> 6;      // wave 0..7: gate col-tiles {wv, wv+8, wv+16, wv+24}
  const int lane = tid & 63;
  const int q    = lane >> 4;     // quad 0..3
  const int col  = lane & 15;

  __shared__ __align__(16) bf16_t xchunk[CT * 16 * LDSW_];  // chunk input, A-layout
  __shared__ __align__(16) bf16_t hbuf[2][16 * LDSW_];      // h state, double-buffered
  __shared__ __align__(16) bf16_t hhist[CT * 16 * LDSW_];   // chunk h history

  // ---- resident weight fragments (bf16, B-layout: lane holds B[k][n], n=col) ----
  bf16x8 wih[4][4], whh[4][4];  // [gate-class c][k-tile kt]
#pragma unroll
  for (int c = 0; c < 4; ++c) {
    const int n = wv * 16 + c * 128 + col;
#pragma unroll
    for (int kt = 0; kt < 4; ++kt) {
      bf16x8 a, b;
#pragma unroll
      for (int jj = 0; jj < 8; ++jj) {
        const int k = kt * 32 + q * 8 + jj;
        a[jj] = (bf16_t)wih_g[(l * H_ + k) * G4_ + n];
        b[jj] = (bf16_t)whh_g[(l * H_ + k) * G4_ + n];
      }
      wih[c][kt] = a;
      whh[c][kt] = b;
    }
  }
  float bias[4];
#pragma unroll
  for (int c = 0; c < 4; ++c) {
    const int n = wv * 16 + c * 128 + col;
    bias[c] = bih_g[l * G4_ + n] + bhh_g[l * G4_ + n];
  }
  bf16x8 wout[4];
  float bo = 0.f;
  const bool has_out = (l == L_ - 1) && (wv < 5);
  if (has_out) {
    const int n = wv * 16 + col;
#pragma unroll
    for (int kt = 0; kt < 4; ++kt) {
      bf16x8 a;
#pragma unroll
      for (int jj = 0; jj < 8; ++jj) {
        const int k = kt * 32 + q * 8 + jj;
        a[jj] = (n < OUT_) ? (bf16_t)wout_g[k * OUT_ + n] : (bf16_t)(0.f);
      }
      wout[kt] = a;
    }
    if (n < OUT_) bo = bout_g[n];
  }

  for (int i = tid; i < 16 * LDSW_; i += 512) hbuf[0][i] = (bf16_t)(0.f);
  float cst[4] = {0.f, 0.f, 0.f, 0.f};  // c-state: rows m=q*4+r, col j=16*wv+col
  __syncthreads();

  int* myprod   = flags + ((l * NG_ + g) << 5);
  int* prevprod = (l > 0) ? flags + (((l - 1) * NG_ + g) << 5) : flags;
  int* mycons   = flags + 1024 + ((l * NG_ + g) << 5);
  int* nextcons = (l < L_ - 1) ? flags + 1024 + (((l + 1) * NG_ + g) << 5) : flags;
  u64* myring  = (l < L_ - 1) ? ring + (size_t)(l * NG_ + g) * RING_T * STEP_U64_ : ring;
  const u64* srcring = (l > 0) ? ring + (size_t)((l - 1) * NG_ + g) * RING_T * STEP_U64_ : ring;

  const int aoff = col * LDSW_ + q * 8;  // A-fragment: m=lane&15, k=q*8+j
  int seen_prod = 0, seen_cons = 0;      // tid0-cached monotonic flags

#pragma unroll 1
  for (int ch = 0; ch < T_ / CT; ++ch) {
    const int t0 = ch * CT;

    // ================= chunk input acquire =================
    if (l == 0) {
      const int m  = tid >> 5;
      const int c4 = (tid & 31) << 2;
#pragma unroll
      for (int tl = 0; tl < CT; ++tl) {
        const int token = xids[(g * BG_ + m) * T_ + t0 + tl];
        const float4 e = *(const float4*)(embed + token * H_ + c4);
        bf16x4 v;
        v[0] = (bf16_t)e.x; v[1] = (bf16_t)e.y; v[2] = (bf16_t)e.z; v[3] = (bf16_t)e.w;
        *(bf16x4*)(&xchunk[(tl * 16 + m) * LDSW_ + c4]) = v;
      }
      __syncthreads();  // xchunk ready
    } else {
      if (tid == 0) {
        const int target = t0 + CT;
        if (seen_prod < target) {
          int v;
          do { v = flag_ld(prevprod); } while (v < target);
          seen_prod = v;
        }
      }
      __syncthreads();  // gate all waves on poll; also ends prior phase-3 reads
      __builtin_amdgcn_fence(__ATOMIC_ACQUIRE, "agent");
      const int idx = tid >> 2;  // row id
      if (idx < CT * 16) {
        const int tl = idx >> 4, m = idx & 15, seg = tid & 3;
        const u64* src = srcring + (size_t)((t0 + tl) & (RING_T - 1)) * STEP_U64_ + m * 32 + seg * 8;
        bf16_t* dst = &xchunk[(tl * 16 + m) * LDSW_ + seg * 32];
#pragma unroll
        for (int j = 0; j < 4; ++j) *(uint4*)(dst + j * 8) = *(const uint4*)(src + j * 2);
      }
      __syncthreads();  // xchunk ready (vmcnt drained)
      if (RING_T < T_ && tid == 0) flag_st(mycons, t0 + CT);
    }

    // slot-reuse back-pressure (only when ring smaller than history)
    if (RING_T < T_ && l < L_ - 1 && t0 + CT > RING_T) {
      if (tid == 0) {
        const int need = t0 + CT - RING_T;
        if (seen_cons < need) {
          int v;
          do { v = flag_ld(nextcons); } while (v < need);
          seen_cons = v;
        }
      }
      __syncthreads();
    }

    // ===== phase 1: dense x-half, gx[tl] = x_tl @ W_ih (static reg indexing) =====
    f32x4 gx[CT][4];
#pragma unroll
    for (int tl = 0; tl < CT; ++tl) {
      bf16x8 xa[4];
      const int xoff = (tl * 16 + col) * LDSW_ + q * 8;
#pragma unroll
      for (int kt = 0; kt < 4; ++kt) xa[kt] = *(const bf16x8*)(&xchunk[xoff + kt * 32]);
#pragma unroll
      for (int c = 0; c < 4; ++c) {
        f32x4 a = (f32x4){0.f, 0.f, 0.f, 0.f};
#pragma unroll
        for (int kt = 0; kt < 4; ++kt)
          a = __builtin_amdgcn_mfma_f32_16x16x32_bf16(xa[kt], wih[c][kt], a, 0, 0, 0);
        gx[tl][c] = a;
      }
    }

    // ===== phase 2: CT recurrent steps, FULLY UNROLLED (1 barrier each) =====
#pragma unroll
    for (int tl = 0; tl < CT; ++tl) {
      const int rb = tl & 1;  // compile-time h buffer parity (CT even)
      bf16x8 ha[4];
#pragma unroll
      for (int kt = 0; kt < 4; ++kt)
        ha[kt] = *(const bf16x8*)(&hbuf[rb][aoff + kt * 32]);
#pragma unroll
      for (int c = 0; c < 4; ++c)
#pragma unroll
        for (int kt = 0; kt < 4; ++kt)
          gx[tl][c] = __builtin_amdgcn_mfma_f32_16x16x32_bf16(ha[kt], whh[c][kt], gx[tl][c], 0, 0, 0);

      float hv[4];
      bf16_t hb[4];
#pragma unroll
      for (int r = 0; r < 4; ++r) {
        const float iv = sigm(gx[tl][0][r] + bias[0]);
        const float fv = sigm(gx[tl][1][r] + bias[1]);
        const float gv = tanh_fast(gx[tl][2][r] + bias[2]);
        const float ov = sigm(gx[tl][3][r] + bias[3]);
        const float cv = fv * cst[r] + iv * gv;
        cst[r] = cv;
        const float h = ov * tanh_fast(cv);
        hv[r] = h;
        hb[r] = (bf16_t)h;
      }

      {
        const int jc = wv * 16 + col;
#pragma unroll
        for (int r = 0; r < 4; ++r) {
          hbuf[rb ^ 1][(q * 4 + r) * LDSW_ + jc] = hb[r];
          hhist[(tl * 16 + q * 4 + r) * LDSW_ + jc] = hb[r];
        }
      }
      if (t0 + tl == T_ - 1) {  // final hT / cT (last step only)
        const int jc = wv * 16 + col;
#pragma unroll
        for (int r = 0; r < 4; ++r) {
          const int b = g * BG_ + q * 4 + r;
          out[HT_OFF_ + (l * B_ + b) * H_ + jc] = hv[r];
          out[CT_OFF_ + (l * B_ + b) * H_ + jc] = cst[r];
        }
      }
      __syncthreads();  // h_t published; hhist[tl] ready
    }

    // ===== phase 3: bulk handoff / batched out-projection =====
    if (l < L_ - 1) {
      const int idx = tid >> 2;
      if (idx < CT * 16) {
        const int tl = idx >> 4, m = idx & 15, seg = tid & 3;
        const bf16_t* src = &hhist[(tl * 16 + m) * LDSW_ + seg * 32];
        u64* dst = myring + (size_t)((t0 + tl) & (RING_T - 1)) * STEP_U64_ + m * 32 + seg * 8;
#pragma unroll
        for (int j = 0; j < 4; ++j) *(uint4*)(dst + j * 2) = *(const uint4*)(src + j * 8);
      }
      __syncthreads();  // vmcnt(0) drain => all ring stores complete
      if (tid == 0) {
        __builtin_amdgcn_fence(__ATOMIC_RELEASE, "agent");
        flag_st(myprod, t0 + CT);
      }
    } else if (has_out) {
      const int n = wv * 16 + col;
#pragma unroll
      for (int tl = 0; tl < CT; ++tl) {
        f32x4 oacc = (f32x4){0.f, 0.f, 0.f, 0.f};
#pragma unroll
        for (int kt = 0; kt < 4; ++kt) {
          const bf16x8 a = *(const bf16x8*)(&hhist[(tl * 16 + col) * LDSW_ + kt * 32 + q * 8]);
          oacc = __builtin_amdgcn_mfma_f32_16x16x32_bf16(a, wout[kt], oacc, 0, 0, 0);
        }
        if (n < OUT_) {
#pragma unroll
          for (int r = 0; r < 4; ++r) {
            const int b = g * BG_ + q * 4 + r;
            out[(b * T_ + (t0 + tl)) * OUT_ + n] = oacc[r] + bo;
          }
        }
      }
    }
  }
}

extern "C" void kernel_launch(void* const* d_in, const int* in_sizes, int n_in,
                              void* d_out, int out_size, void* d_ws, size_t ws_size,
                              hipStream_t stream) {
  (void)in_sizes; (void)n_in; (void)out_size;
  const int*   x     = (const int*)d_in[0];
  const float* embed = (const float*)d_in[1];
  const float* w_ih  = (const float*)d_in[2];
  const float* b_ih  = (const float*)d_in[3];
  const float* w_hh  = (const float*)d_in[4];
  const float* b_hh  = (const float*)d_in[5];
  const float* w_out = (const float*)d_in[6];
  const float* b_out = (const float*)d_in[7];
  float* out = (float*)d_out;

  int* flags = (int*)d_ws;                     // 8 KB: prod@0, cons@4KB
  u64* ring  = (u64*)((char*)d_ws + 8192);

  hipLaunchKernelGGL(zero_flags, dim3(2), dim3(1024), 0, stream, flags);

  auto need = [&](int ring_t) { return (size_t)8192 + (size_t)28 * ring_t * 4096; };

  if (ws_size >= need(512)) {        // 57 MB: full history, no back-pressure
    hipLaunchKernelGGL((lstm_pipe<4, 512>), dim3(L_ * NG_), dim3(512), 0, stream,
                       x, embed, w_ih, b_ih, w_hh, b_hh, w_out, b_out, out, flags, ring);
  } else if (ws_size >= need(16)) {  // 1.8 MB
    hipLaunchKernelGGL((lstm_pipe<4, 16>), dim3(L_ * NG_), dim3(512), 0, stream,
                       x, embed, w_ih, b_ih, w_hh, b_hh, w_out, b_out, out, flags, ring);
  } else if (ws_size >= need(8)) {   // 0.92 MB
    hipLaunchKernelGGL((lstm_pipe<4, 8>), dim3(L_ * NG_), dim3(512), 0, stream,
                       x, embed, w_ih, b_ih, w_hh, b_hh, w_out, b_out, out, flags, ring);
  } else {                           // 0.47 MB worst case
    hipLaunchKernelGGL((lstm_pipe<4, 4>), dim3(L_ * NG_), dim3(512), 0, stream,
                       x, embed, w_ih, b_ih, w_hh, b_hh, w_out, b_out, out, flags, ring);
  }
}

// Round 7
// 1151.992 us; speedup vs baseline: 1.8163x; 1.2637x over previous
//
#include <hip/hip_runtime.h>
#include <hip/hip_bf16.h>

// DeepLSTM on MI355X — v7: step-loop issue diet.
//
// v6 post-mortem: period set by the phase-2 step body. Headline bug:
// 1/(1+e) and (1-e)/(1+e) compile to FULL IEEE division (~10 VALU each,
// no fast-math) -> 20 div expansions/step/lane ~ 200 extra VALU. v7:
//  - __builtin_amdgcn_rcpf: sigm = rcp(1+exp(-x)); tanh(x) = sign(x)*(2*rcp(1+exp(-2|x|))-1)
//  - bias folded into phase-1 MFMA accumulator init (not re-added per step)
//  - ONE circular LDS h buffer (hist[CT], step tl reads hist[(tl+CT-1)%CT]);
//    drop hbuf; hist also feeds ring stores + L7 out-projection
//  - per-step fire-and-forget ring stores; ONE drain barrier per chunk
//  - merged boundary: mycons publish BEFORE polls (deadlock-free, RING_T>=2*CT)
//
// Grid: 32 blocks x 512 threads; block (l,g) = layer l, batch group g (16 rows).
// ws: [0,8KB) flags (prod@0, cons@4KB, 128B stride); [8KB,...) ring
//     [pair][RING_T][16][128] bf16.

#define T_ 512
#define L_ 8
#define H_ 128
#define G4_ 512
#define OUT_ 65
#define B_ 64
#define NG_ 4
#define BG_ 16
#define LDSW_ 136                          // padded LDS row stride (bf16)
#define HT_OFF_ (B_ * T_ * OUT_)           // 2129920
#define CT_OFF_ (HT_OFF_ + L_ * B_ * H_)   // 2195456
#define STEP_U64_ 512                      // one step's h-tile: 16x128 bf16 = 4KB

typedef __bf16 bf16_t;
typedef bf16_t bf16x8 __attribute__((ext_vector_type(8)));
typedef bf16_t bf16x4 __attribute__((ext_vector_type(4)));
typedef float f32x4 __attribute__((ext_vector_type(4)));
typedef unsigned long long u64;

__device__ __forceinline__ float rcpf(float x) { return __builtin_amdgcn_rcpf(x); }
__device__ __forceinline__ float sigm(float x) {
  return rcpf(1.f + __expf(-x));  // v_mul, v_exp, v_add, v_rcp
}
__device__ __forceinline__ float tanh_fast(float x) {
  // tanh(|x|) = 2/(1+exp(-2|x|)) - 1 ; restore sign. No division, no overflow.
  const float e = __expf(-2.f * fabsf(x));
  const float r = 2.f * rcpf(1.f + e) - 1.f;  // fma(2, u, -1)
  return copysignf(r, x);
}
__device__ __forceinline__ int flag_ld(int* p) {
  return __hip_atomic_load(p, __ATOMIC_RELAXED, __HIP_MEMORY_SCOPE_AGENT);
}
__device__ __forceinline__ void flag_st(int* p, int v) {
  __hip_atomic_store(p, v, __ATOMIC_RELAXED, __HIP_MEMORY_SCOPE_AGENT);
}

__global__ void zero_flags(int* flags) { flags[blockIdx.x * 1024 + threadIdx.x] = 0; }

template <int CT, int RING_T>
__global__ __launch_bounds__(512, 2)
void lstm_pipe(const int* __restrict__ xids, const float* __restrict__ embed,
               const float* __restrict__ wih_g, const float* __restrict__ bih_g,
               const float* __restrict__ whh_g, const float* __restrict__ bhh_g,
               const float* __restrict__ wout_g, const float* __restrict__ bout_g,
               float* __restrict__ out, int* __restrict__ flags,
               u64* __restrict__ ring) {
  static_assert(RING_T >= 2 * CT || RING_T >= T_, "need >=2 chunks of ring slack");
  constexpr int NCH = T_ / CT;
  const int l    = blockIdx.x >> 2;
  const int g    = blockIdx.x & 3;
  const int tid  = threadIdx.x;
  const int wv   = tid >> 6;      // wave 0..7: gate col-tiles {wv, wv+8, wv+16, wv+24}
  const int lane = tid & 63;
  const int q    = lane >> 4;     // quad 0..3
  const int col  = lane & 15;

  __shared__ __align__(16) bf16_t xchunk[CT][16 * LDSW_];  // chunk input, A-layout
  __shared__ __align__(16) bf16_t hist[CT][16 * LDSW_];    // circular h history

  // ---- resident weight fragments (bf16, B-layout: lane holds B[k][n], n=col) ----
  bf16x8 wih[4][4], whh[4][4];  // [gate-class c][k-tile kt]
#pragma unroll
  for (int c = 0; c < 4; ++c) {
    const int n = wv * 16 + c * 128 + col;
#pragma unroll
    for (int kt = 0; kt < 4; ++kt) {
      bf16x8 a, b;
#pragma unroll
      for (int jj = 0; jj < 8; ++jj) {
        const int k = kt * 32 + q * 8 + jj;
        a[jj] = (bf16_t)wih_g[(l * H_ + k) * G4_ + n];
        b[jj] = (bf16_t)whh_g[(l * H_ + k) * G4_ + n];
      }
      wih[c][kt] = a;
      whh[c][kt] = b;
    }
  }
  float bias[4];
#pragma unroll
  for (int c = 0; c < 4; ++c) {
    const int n = wv * 16 + c * 128 + col;
    bias[c] = bih_g[l * G4_ + n] + bhh_g[l * G4_ + n];
  }
  bf16x8 wout[4];
  float bo = 0.f;
  const bool has_out = (l == L_ - 1) && (wv < 5);
  if (has_out) {
    const int n = wv * 16 + col;
#pragma unroll
    for (int kt = 0; kt < 4; ++kt) {
      bf16x8 a;
#pragma unroll
      for (int jj = 0; jj < 8; ++jj) {
        const int k = kt * 32 + q * 8 + jj;
        a[jj] = (n < OUT_) ? (bf16_t)wout_g[k * OUT_ + n] : (bf16_t)(0.f);
      }
      wout[kt] = a;
    }
    if (n < OUT_) bo = bout_g[n];
  }

  int* myprod   = flags + ((l * NG_ + g) << 5);
  int* prevprod = (l > 0) ? flags + (((l - 1) * NG_ + g) << 5) : flags;
  int* mycons   = flags + 1024 + ((l * NG_ + g) << 5);
  int* nextcons = (l < L_ - 1) ? flags + 1024 + (((l + 1) * NG_ + g) << 5) : flags;
  u64* myring  = (l < L_ - 1) ? ring + (size_t)(l * NG_ + g) * RING_T * STEP_U64_ : ring;
  const u64* srcring = (l > 0) ? ring + (size_t)((l - 1) * NG_ + g) * RING_T * STEP_U64_ : ring;

  const int aoff = col * LDSW_ + q * 8;  // A-fragment: m=lane&15, k=q*8+j
  float cst[4] = {0.f, 0.f, 0.f, 0.f};  // c-state: rows m=q*4+r, col j=16*wv+col
  int seen_prod = 0, seen_cons = 0;

  // ---- prologue: zero h_{-1} (hist[CT-1]); acquire chunk 0 ----
  for (int i = tid; i < 16 * LDSW_; i += 512) hist[CT - 1][i] = (bf16_t)(0.f);
  if (l == 0) {
    const int m  = tid >> 5;
    const int c4 = (tid & 31) << 2;
#pragma unroll
    for (int tl = 0; tl < CT; ++tl) {
      const int token = xids[(g * BG_ + m) * T_ + tl];
      const float4 e = *(const float4*)(embed + token * H_ + c4);
      bf16x4 v;
      v[0] = (bf16_t)e.x; v[1] = (bf16_t)e.y; v[2] = (bf16_t)e.z; v[3] = (bf16_t)e.w;
      *(bf16x4*)(&xchunk[tl][m * LDSW_ + c4]) = v;
    }
  } else {
    if (tid == 0) {
      int v;
      do { v = flag_ld(prevprod); } while (v < CT);
      seen_prod = v;
    }
    __syncthreads();
    __builtin_amdgcn_fence(__ATOMIC_ACQUIRE, "agent");
    const int idx = tid >> 2;
    if (idx < CT * 16) {
      const int tl = idx >> 4, m = idx & 15, seg = tid & 3;
      const u64* src = srcring + (size_t)(tl & (RING_T - 1)) * STEP_U64_ + m * 32 + seg * 8;
      bf16_t* dst = &xchunk[tl][m * LDSW_ + seg * 32];
#pragma unroll
      for (int j = 0; j < 4; ++j) *(uint4*)(dst + j * 8) = *(const uint4*)(src + j * 2);
    }
  }
  __syncthreads();  // hist[CT-1] zeroed + xchunk(0) ready

#pragma unroll 1
  for (int ch = 0; ch < NCH; ++ch) {
    const int t0 = ch * CT;

    // ===== phase 1: dense x-half, gx[tl][c] = bias[c] + x_tl @ W_ih =====
    f32x4 gx[CT][4];
#pragma unroll
    for (int tl = 0; tl < CT; ++tl) {
      bf16x8 xa[4];
#pragma unroll
      for (int kt = 0; kt < 4; ++kt)
        xa[kt] = *(const bf16x8*)(&xchunk[tl][aoff + kt * 32]);
#pragma unroll
      for (int c = 0; c < 4; ++c) {
        f32x4 a = (f32x4){bias[c], bias[c], bias[c], bias[c]};
#pragma unroll
        for (int kt = 0; kt < 4; ++kt)
          a = __builtin_amdgcn_mfma_f32_16x16x32_bf16(xa[kt], wih[c][kt], a, 0, 0, 0);
        gx[tl][c] = a;
      }
    }

    // ===== phase 2: CT recurrent steps (1 barrier each), per-step ring store =====
#pragma unroll
    for (int tl = 0; tl < CT; ++tl) {
      bf16x8 ha[4];
#pragma unroll
      for (int kt = 0; kt < 4; ++kt)
        ha[kt] = *(const bf16x8*)(&hist[(tl + CT - 1) % CT][aoff + kt * 32]);
#pragma unroll
      for (int c = 0; c < 4; ++c)
#pragma unroll
        for (int kt = 0; kt < 4; ++kt)
          gx[tl][c] = __builtin_amdgcn_mfma_f32_16x16x32_bf16(ha[kt], whh[c][kt], gx[tl][c], 0, 0, 0);

      float hv[4];
      bf16_t hb[4];
#pragma unroll
      for (int r = 0; r < 4; ++r) {
        const float iv = sigm(gx[tl][0][r]);
        const float fv = sigm(gx[tl][1][r]);
        const float gv = tanh_fast(gx[tl][2][r]);
        const float ov = sigm(gx[tl][3][r]);
        const float cv = fv * cst[r] + iv * gv;
        cst[r] = cv;
        const float h = ov * tanh_fast(cv);
        hv[r] = h;
        hb[r] = (bf16_t)h;
      }
      {
        const int jc = wv * 16 + col;
#pragma unroll
        for (int r = 0; r < 4; ++r)
          hist[tl][(q * 4 + r) * LDSW_ + jc] = hb[r];
      }
      if (t0 + tl == T_ - 1) {  // final hT / cT
        const int jc = wv * 16 + col;
#pragma unroll
        for (int r = 0; r < 4; ++r) {
          const int b = g * BG_ + q * 4 + r;
          out[HT_OFF_ + (l * B_ + b) * H_ + jc] = hv[r];
          out[CT_OFF_ + (l * B_ + b) * H_ + jc] = cst[r];
        }
      }
      __syncthreads();  // hist[tl] published block-wide

      if (l < L_ - 1) {  // fire-and-forget; drained at the boundary barrier
        const u64 val = *(const u64*)(&hist[tl][(tid >> 5) * LDSW_ + ((tid & 31) << 2)]);
        myring[(size_t)((t0 + tl) & (RING_T - 1)) * STEP_U64_ + tid] = val;
      }
    }

    // ===== L7: batched out-projection from hist =====
    if (has_out) {
      const int n = wv * 16 + col;
#pragma unroll
      for (int tl = 0; tl < CT; ++tl) {
        f32x4 oacc = (f32x4){0.f, 0.f, 0.f, 0.f};
#pragma unroll
        for (int kt = 0; kt < 4; ++kt) {
          const bf16x8 a = *(const bf16x8*)(&hist[tl][col * LDSW_ + kt * 32 + q * 8]);
          oacc = __builtin_amdgcn_mfma_f32_16x16x32_bf16(a, wout[kt], oacc, 0, 0, 0);
        }
        if (n < OUT_) {
#pragma unroll
          for (int r = 0; r < 4; ++r) {
            const int b = g * BG_ + q * 4 + r;
            out[(b * T_ + (t0 + tl)) * OUT_ + n] = oacc[r] + bo;
          }
        }
      }
    }

    // ===== boundary: drain + publish + acquire(ch+1) =====
    if (ch + 1 < NCH) {
      if (tid == 0) {
        if (RING_T < T_ && l > 0) flag_st(mycons, t0 + CT);  // BEFORE polls (no deadlock)
        if (l > 0) {
          const int target = t0 + 2 * CT;
          if (seen_prod < target) {
            int v;
            do { v = flag_ld(prevprod); } while (v < target);
            seen_prod = v;
          }
        }
        if (RING_T < T_ && l < L_ - 1 && t0 + 2 * CT > RING_T) {
          const int need = t0 + 2 * CT - RING_T;
          if (seen_cons < need) {
            int v;
            do { v = flag_ld(nextcons); } while (v < need);
            seen_cons = v;
          }
        }
      }
      __syncthreads();  // drains all chunk-ch ring stores (vmcnt at barrier); gates polls
      if (l < L_ - 1 && tid == 0) {
        __builtin_amdgcn_fence(__ATOMIC_RELEASE, "agent");
        flag_st(myprod, t0 + CT);
      }
      if (l == 0) {
        const int m  = tid >> 5;
        const int c4 = (tid & 31) << 2;
#pragma unroll
        for (int tl = 0; tl < CT; ++tl) {
          const int token = xids[(g * BG_ + m) * T_ + t0 + CT + tl];
          const float4 e = *(const float4*)(embed + token * H_ + c4);
          bf16x4 v;
          v[0] = (bf16_t)e.x; v[1] = (bf16_t)e.y; v[2] = (bf16_t)e.z; v[3] = (bf16_t)e.w;
          *(bf16x4*)(&xchunk[tl][m * LDSW_ + c4]) = v;
        }
      } else {
        __builtin_amdgcn_fence(__ATOMIC_ACQUIRE, "agent");
        const int idx = tid >> 2;
        if (idx < CT * 16) {
          const int tl = idx >> 4, m = idx & 15, seg = tid & 3;
          const u64* src = srcring + (size_t)((t0 + CT + tl) & (RING_T - 1)) * STEP_U64_ + m * 32 + seg * 8;
          bf16_t* dst = &xchunk[tl][m * LDSW_ + seg * 32];
#pragma unroll
          for (int j = 0; j < 4; ++j) *(uint4*)(dst + j * 8) = *(const uint4*)(src + j * 2);
        }
      }
      __syncthreads();  // xchunk(ch+1) ready
    } else if (l < L_ - 1) {
      __syncthreads();  // drain last chunk's ring stores
      if (tid == 0) {
        __builtin_amdgcn_fence(__ATOMIC_RELEASE, "agent");
        flag_st(myprod, T_);
      }
    }
  }
}

extern "C" void kernel_launch(void* const* d_in, const int* in_sizes, int n_in,
                              void* d_out, int out_size, void* d_ws, size_t ws_size,
                              hipStream_t stream) {
  (void)in_sizes; (void)n_in; (void)out_size;
  const int*   x     = (const int*)d_in[0];
  const float* embed = (const float*)d_in[1];
  const float* w_ih  = (const float*)d_in[2];
  const float* b_ih  = (const float*)d_in[3];
  const float* w_hh  = (const float*)d_in[4];
  const float* b_hh  = (const float*)d_in[5];
  const float* w_out = (const float*)d_in[6];
  const float* b_out = (const float*)d_in[7];
  float* out = (float*)d_out;

  int* flags = (int*)d_ws;                     // 8 KB: prod@0, cons@4KB
  u64* ring  = (u64*)((char*)d_ws + 8192);

  hipLaunchKernelGGL(zero_flags, dim3(2), dim3(1024), 0, stream, flags);

  auto need = [&](int ring_t) { return (size_t)8192 + (size_t)28 * ring_t * 4096; };

  if (ws_size >= need(512)) {        // 57 MB: full history, no back-pressure
    hipLaunchKernelGGL((lstm_pipe<4, 512>), dim3(L_ * NG_), dim3(512), 0, stream,
                       x, embed, w_ih, b_ih, w_hh, b_hh, w_out, b_out, out, flags, ring);
  } else if (ws_size >= need(16)) {  // 1.8 MB
    hipLaunchKernelGGL((lstm_pipe<4, 16>), dim3(L_ * NG_), dim3(512), 0, stream,
                       x, embed, w_ih, b_ih, w_hh, b_hh, w_out, b_out, out, flags, ring);
  } else if (ws_size >= need(8)) {   // 0.92 MB
    hipLaunchKernelGGL((lstm_pipe<4, 8>), dim3(L_ * NG_), dim3(512), 0, stream,
                       x, embed, w_ih, b_ih, w_hh, b_hh, w_out, b_out, out, flags, ring);
  } else {                           // 0.47 MB worst case
    hipLaunchKernelGGL((lstm_pipe<2, 4>), dim3(L_ * NG_), dim3(512), 0, stream,
                       x, embed, w_ih, b_ih, w_hh, b_hh, w_out, b_out, out, flags, ring);
  }
}